// Round 8
// baseline (155.839 us; speedup 1.0000x reference)
//
#include <hip/hip_runtime.h>

typedef unsigned short u16;
typedef __bf16 bf16x8 __attribute__((ext_vector_type(8)));
typedef float f32x4 __attribute__((ext_vector_type(4)));
typedef float f32x16 __attribute__((ext_vector_type(16)));

#define D_MODEL 1024
#define NH 16
#define DKD 64
#define BB 2
#define SS 2048
// log2(e)/8: folded into Q at projection time
#define QSCL 0.18033688011112042f

__device__ __forceinline__ u16 f2bf(float f) {
  union { float f; unsigned u; } x; x.f = f;
  unsigned r = x.u + 0x7fffu + ((x.u >> 16) & 1u);
  return (u16)(r >> 16);
}

__device__ __forceinline__ void gld16(const u16* g, u16* l) {
  __builtin_amdgcn_global_load_lds((__attribute__((address_space(1))) void*)(g),
                                   (__attribute__((address_space(3))) void*)(l),
                                   16, 0, 0);
}

// ---------------- prep: fp32 -> bf16 activation convert ----------------
extern "C" __global__ void __launch_bounds__(256) kprep_conv(
    const float* __restrict__ q, const float* __restrict__ k, const float* __restrict__ v,
    u16* __restrict__ xq, u16* __restrict__ xk, u16* __restrict__ xv)
{
  int z = blockIdx.y;
  const float* s = z == 0 ? q : (z == 1 ? k : v);
  u16* d = z == 0 ? xq : (z == 1 ? xk : xv);
  int i = (blockIdx.x * 256 + threadIdx.x) * 4;
  float4 val = *(const float4*)(s + i);
  ushort4 o;
  o.x = f2bf(val.x); o.y = f2bf(val.y); o.z = f2bf(val.z); o.w = f2bf(val.w);
  *(ushort4*)(d + i) = o;
}

// ---------------- prep: weight transpose + bf16 convert ----------------
extern "C" __global__ void __launch_bounds__(256) kprep_wt(
    const float* __restrict__ w0, const float* __restrict__ w1,
    const float* __restrict__ w2, const float* __restrict__ w3,
    u16* __restrict__ o0, u16* __restrict__ o1, u16* __restrict__ o2, u16* __restrict__ o3)
{
  const float* src; u16* dst;
  switch (blockIdx.z) {
    case 0: src = w0; dst = o0; break;
    case 1: src = w1; dst = o1; break;
    case 2: src = w2; dst = o2; break;
    default: src = w3; dst = o3; break;
  }
  __shared__ float t[32][33];
  int n0 = blockIdx.x * 32, k0 = blockIdx.y * 32;
  int tx = threadIdx.x & 31, ty = threadIdx.x >> 5;
  #pragma unroll
  for (int i = 0; i < 32; i += 8)
    t[ty + i][tx] = src[(k0 + ty + i) * D_MODEL + n0 + tx];
  __syncthreads();
  #pragma unroll
  for (int i = 0; i < 32; i += 8)
    dst[(size_t)(n0 + ty + i) * D_MODEL + k0 + tx] = f2bf(t[tx][ty + i]);
}

// ---------------- prep: log2(weights + 1e-20) - 16 (fixed-max softmax bias) ----------------
extern "C" __global__ void __launch_bounds__(256) klw(
    const float* __restrict__ w, float* __restrict__ lw)
{
  int i = blockIdx.x * 256 + threadIdx.x;
  if (i < BB * SS) lw[i] = log2f(w[i] + 1e-20f) - 16.0f;
}

// ---------------- V transpose: (b,h,s,dk) -> (b,h,dk,s) ----------------
extern "C" __global__ void __launch_bounds__(256) ktrans_v(
    const u16* __restrict__ src, u16* __restrict__ dst)
{
  __shared__ u16 T[64][72];
  int bh = blockIdx.y; int s0 = blockIdx.x * 64;
  int tid = threadIdx.x;
  int r = tid >> 3, c = (tid & 7) * 8;
  #pragma unroll
  for (int i = 0; i < 2; ++i)
    *(bf16x8*)&T[r + i * 32][c] = *(const bf16x8*)&src[((size_t)bh * SS + s0 + r + i * 32) * DKD + c];
  __syncthreads();
  #pragma unroll
  for (int i = 0; i < 2; ++i) {
    int dk = r + i * 32;
    ushort4 o0, o1;
    o0.x = T[c + 0][dk]; o0.y = T[c + 1][dk]; o0.z = T[c + 2][dk]; o0.w = T[c + 3][dk];
    o1.x = T[c + 4][dk]; o1.y = T[c + 5][dk]; o1.z = T[c + 6][dk]; o1.w = T[c + 7][dk];
    *(ushort4*)&dst[((size_t)bh * DKD + dk) * SS + s0 + c] = o0;
    *(ushort4*)&dst[((size_t)bh * DKD + dk) * SS + s0 + c + 4] = o1;
  }
}

// ---------------- shared GEMM core: C(128x128) = A(128xK) * Bt(128xK)^T ----------------
__device__ __forceinline__ void gemm_tile(const u16* __restrict__ Ag, const u16* __restrict__ Bg,
                                          u16* As, u16* Bs, f32x4 acc[4][4], int tid)
{
  int lane = tid & 63;
  int lr = lane & 15, lg = lane >> 4;
  int w = tid >> 6, wr = w >> 1, wc = w & 1;
  for (int k0 = 0; k0 < D_MODEL; k0 += 32) {
    #pragma unroll
    for (int c = 0; c < 2; ++c) {
      int idx = tid + c * 256;
      int row = idx >> 2, col = (idx & 3) * 8;
      gld16(Ag + row * D_MODEL + k0 + col, As + idx * 8);
      gld16(Bg + row * D_MODEL + k0 + col, Bs + idx * 8);
    }
    __syncthreads();
    bf16x8 af[4], bfr[4];
    #pragma unroll
    for (int mi = 0; mi < 4; ++mi)
      af[mi] = *(const bf16x8*)(As + (wr * 64 + mi * 16 + lr) * 32 + lg * 8);
    #pragma unroll
    for (int nj = 0; nj < 4; ++nj)
      bfr[nj] = *(const bf16x8*)(Bs + (wc * 64 + nj * 16 + lr) * 32 + lg * 8);
    #pragma unroll
    for (int mi = 0; mi < 4; ++mi)
      #pragma unroll
      for (int nj = 0; nj < 4; ++nj)
        acc[mi][nj] = __builtin_amdgcn_mfma_f32_16x16x32_bf16(af[mi], bfr[nj], acc[mi][nj], 0, 0, 0);
    __syncthreads();
  }
}

// ---------------- fused QKV projection ----------------
// z==0: Q scaled by QSCL. All outputs layout (b,h,s,dk).
extern "C" __global__ void __launch_bounds__(256) kgemm_qkv(
    const u16* __restrict__ xq, const u16* __restrict__ xk, const u16* __restrict__ xv,
    const u16* __restrict__ wqt, const u16* __restrict__ wkt, const u16* __restrict__ wvt,
    const float* __restrict__ bq, const float* __restrict__ bk, const float* __restrict__ bv,
    u16* __restrict__ Qb, u16* __restrict__ Kb, u16* __restrict__ Vb)
{
  __shared__ u16 As[128 * 32], Bs[128 * 32];
  int z = blockIdx.z;
  const u16* X  = z == 0 ? xq : (z == 1 ? xk : xv);
  const u16* Wt = z == 0 ? wqt : (z == 1 ? wkt : wvt);
  const float* bias = z == 0 ? bq : (z == 1 ? bk : bv);
  u16* dst = z == 0 ? Qb : (z == 1 ? Kb : Vb);
  int tid = threadIdx.x;
  f32x4 zero = {0.f, 0.f, 0.f, 0.f};
  f32x4 acc[4][4];
  #pragma unroll
  for (int i = 0; i < 4; ++i)
    #pragma unroll
    for (int j = 0; j < 4; ++j) acc[i][j] = zero;
  int m0 = blockIdx.y * 128, n0 = blockIdx.x * 128;
  gemm_tile(X + (size_t)m0 * D_MODEL, Wt + (size_t)n0 * D_MODEL, As, Bs, acc, tid);
  int lane = tid & 63, lr = lane & 15, lg = lane >> 4;
  int w = tid >> 6, wr = w >> 1, wc = w & 1;
  float scl = (z == 0) ? QSCL : 1.0f;
  #pragma unroll
  for (int mi = 0; mi < 4; ++mi)
    #pragma unroll
    for (int nj = 0; nj < 4; ++nj) {
      int n = n0 + wc * 64 + nj * 16 + lr;
      float bs = bias[n];
      int h = n >> 6, dk = n & 63;
      #pragma unroll
      for (int j = 0; j < 4; ++j) {
        int m = m0 + wr * 64 + mi * 16 + lg * 4 + j;
        int b = m >> 11, s = m & 2047;
        dst[(((size_t)(b * NH + h)) * SS + s) * DKD + dk] = f2bf((acc[mi][nj][j] + bs) * scl);
      }
    }
}

// ---------------- output projection ----------------
extern "C" __global__ void __launch_bounds__(256) kgemm_o(
    const u16* __restrict__ AO, const u16* __restrict__ wot,
    const float* __restrict__ bo, float* __restrict__ out)
{
  __shared__ u16 As[128 * 32], Bs[128 * 32];
  int tid = threadIdx.x;
  f32x4 zero = {0.f, 0.f, 0.f, 0.f};
  f32x4 acc[4][4];
  #pragma unroll
  for (int i = 0; i < 4; ++i)
    #pragma unroll
    for (int j = 0; j < 4; ++j) acc[i][j] = zero;
  int m0 = blockIdx.y * 128, n0 = blockIdx.x * 128;
  gemm_tile(AO + (size_t)m0 * D_MODEL, wot + (size_t)n0 * D_MODEL, As, Bs, acc, tid);
  int lane = tid & 63, lr = lane & 15, lg = lane >> 4;
  int w = tid >> 6, wr = w >> 1, wc = w & 1;
  #pragma unroll
  for (int mi = 0; mi < 4; ++mi)
    #pragma unroll
    for (int nj = 0; nj < 4; ++nj) {
      int n = n0 + wc * 64 + nj * 16 + lr;
      float bs = bo[n];
      #pragma unroll
      for (int j = 0; j < 4; ++j) {
        int m = m0 + wr * 64 + mi * 16 + lg * 4 + j;
        out[(size_t)m * D_MODEL + n] = acc[mi][nj][j] + bs;
      }
    }
}

// ---------------- flash attention: 32x32 MFMA, in-register P via permlane32_swap ----------------
// Qb: (b,h,s,dk) bf16 PRE-SCALED by log2(e)/8. Kb: (b,h,s,dk). Vt: (b,h,dk,s).
// lw2: (b,s) f32 = log2(w+1e-20)-16 (staged to LDS). AO: (b,s,1024) bf16.
// Per block: 128 q rows, 4 waves x 32q. Per 64-kv tile:
//   St[nh] = lw + K*Q^T  (2 x mfma32x32x16, kv-half nh; C: col=q=lane&31, row=(r&3)+8(r>>2)+4hi)
//   p = exp2(St); pack pairs (cvt_pk) -> wd[nh][0..7]; Pb[c] B-frags via 2 permlane32_swap each:
//     slot s of chunk c sources word j0+(s&1) of half (s>>1): s1=swap(wd[j0],wd[j0+2]) ->
//     Pb = {s1[0], s2[0], s1[1], s2[1]}  (r0={a_lo,b_lo}, r1={a_hi,b_hi})
//   O^T += V^T * Pb ; lsum += ones * Pb  (every lane ends with full denom for its q)
// Pipeline: triple-buffered K/V, prefetch depth 2, s_barrier + counted vmcnt(4).
extern "C" __global__ void __launch_bounds__(256, 2) kattn(
    const u16* __restrict__ Qb, const u16* __restrict__ Kb, const u16* __restrict__ Vt,
    const float* __restrict__ lw2, u16* __restrict__ AO)
{
  __shared__ __align__(16) u16 Ks[3][64 * 64];
  __shared__ __align__(16) u16 Vs[3][64 * 64];
  __shared__ __align__(16) float lwf[SS];

  int tid = threadIdx.x, lane = tid & 63, w = tid >> 6;  // w 0..3
  int lq = lane & 31, hi = lane >> 5;

  // XCD-clustered decode: each XCD owns 4 heads x all 16 q-tiles (K/V L2-resident)
  int n = blockIdx.x;                  // 0..511
  int xcd = n & 7, slot = n >> 3;
  int bh = xcd + 8 * (slot >> 4);
  int q0 = (slot & 15) * 128;
  int b = bh >> 4, h = bh & 15;

  const u16* Qg = Qb + ((size_t)bh * SS + q0 + w * 32) * DKD;
  const u16* Kg = Kb + (size_t)bh * SS * DKD;
  const u16* Vg = Vt + (size_t)bh * DKD * SS;   // rows = dk, cols = s
  const float* lwb = lw2 + b * SS;

  // stage lw row into LDS
  #pragma unroll
  for (int i = 0; i < 2; ++i) {
    int idx = tid + i * 256;
    *(float4*)&lwf[idx * 4] = *(const float4*)(lwb + idx * 4);
  }

  // Q B-frags: B[k = kc*16 + hi*8 + i][q = lq]
  bf16x8 qf[4];
  #pragma unroll
  for (int kc = 0; kc < 4; ++kc)
    qf[kc] = *(const bf16x8*)(Qg + lq * DKD + kc * 16 + hi * 8);

  // all-ones bf16 A-fragment for the lsum MFMA
  union { u16 s[8]; bf16x8 v; } onesu;
  #pragma unroll
  for (int i = 0; i < 8; ++i) onesu.s[i] = 0x3F80;
  bf16x8 onesv = onesu.v;

  f32x16 acco[2] = {}, acc_l = {};

  // staging: LDS[row][c3] = Global[row][c3 ^ (row&7)] (linear dest for gld16)
  int srow0 = tid >> 3, sc0 = ((tid & 7) ^ (srow0 & 7)) * 8;
  int srow1 = srow0 + 32, sc1 = ((tid & 7) ^ (srow1 & 7)) * 8;

#define STAGE(t, bi) do { \
    gld16(Kg + (size_t)((t) * 64 + srow0) * DKD + sc0, &Ks[bi][tid * 8]); \
    gld16(Kg + (size_t)((t) * 64 + srow1) * DKD + sc1, &Ks[bi][(tid + 256) * 8]); \
    gld16(Vg + (size_t)srow0 * SS + (t) * 64 + sc0, &Vs[bi][tid * 8]); \
    gld16(Vg + (size_t)srow1 * SS + (t) * 64 + sc1, &Vs[bi][(tid + 256) * 8]); \
  } while (0)

  const int NT = SS / 64;
  STAGE(0, 0);
  STAGE(1, 1);
  for (int t = 0; t < NT; ++t) {
    if (t < NT - 1) asm volatile("s_waitcnt vmcnt(4) lgkmcnt(0)" ::: "memory");
    else            asm volatile("s_waitcnt vmcnt(0) lgkmcnt(0)" ::: "memory");
    __builtin_amdgcn_s_barrier();
    __builtin_amdgcn_sched_barrier(0);
    if (t + 2 < NT) STAGE(t + 2, (t + 2) % 3);
    int bi = t % 3;
    int kv0 = t * 64;

    // ---- St[nh] init from lw: row(reg r) = (r&3) + 8*(r>>2) + 4*hi ----
    f32x16 st[2];
    #pragma unroll
    for (int nh = 0; nh < 2; ++nh)
      #pragma unroll
      for (int g = 0; g < 4; ++g) {
        f32x4 lv = *(const f32x4*)&lwf[kv0 + nh * 32 + 4 * hi + 8 * g];
        st[nh][4 * g + 0] = lv[0]; st[nh][4 * g + 1] = lv[1];
        st[nh][4 * g + 2] = lv[2]; st[nh][4 * g + 3] = lv[3];
      }

    // ---- St += K * Q^T ----
    __builtin_amdgcn_s_setprio(1);
    #pragma unroll
    for (int kc = 0; kc < 4; ++kc) {
      bf16x8 kf0 = *(const bf16x8*)&Ks[bi][(lq) * 64      + (((kc * 2 + hi) ^ (lq & 7)) * 8)];
      bf16x8 kf1 = *(const bf16x8*)&Ks[bi][(32 + lq) * 64 + (((kc * 2 + hi) ^ (lq & 7)) * 8)];
      st[0] = __builtin_amdgcn_mfma_f32_32x32x16_bf16(kf0, qf[kc], st[0], 0, 0, 0);
      st[1] = __builtin_amdgcn_mfma_f32_32x32x16_bf16(kf1, qf[kc], st[1], 0, 0, 0);
    }
    __builtin_amdgcn_s_setprio(0);

    // ---- p = exp2(st); pack pairs to words wd[nh][r2] = (p[2r2], p[2r2+1]) ----
    unsigned wd[2][8];
    #pragma unroll
    for (int nh = 0; nh < 2; ++nh)
      #pragma unroll
      for (int r2 = 0; r2 < 8; ++r2) {
        float plo = exp2f(st[nh][2 * r2]);
        float phi = exp2f(st[nh][2 * r2 + 1]);
        union { unsigned u; __bf16 b2[2]; } cv;
        cv.b2[0] = (__bf16)plo; cv.b2[1] = (__bf16)phi;
        wd[nh][r2] = cv.u;
      }

    // ---- Pb[c] B-frags via permlane32_swap (no LDS round-trip) ----
    // chunk c: kv = c*16 + hi*8 + i; nh = c>>1, j0 = 4*(c&1)
    // s1 = swap(wd[j0], wd[j0+2]): s1[0] = {a_lo,b_lo} -> slot i=0,1 ; s1[1] = {a_hi,b_hi} -> slot i=4,5
    // s2 = swap(wd[j0+1], wd[j0+3]): slots i=2,3 and i=6,7
    bf16x8 Pb[4];
    #pragma unroll
    for (int c = 0; c < 4; ++c) {
      int nh = c >> 1, j0 = 4 * (c & 1);
      auto s1 = __builtin_amdgcn_permlane32_swap(wd[nh][j0 + 0], wd[nh][j0 + 2], false, false);
      auto s2 = __builtin_amdgcn_permlane32_swap(wd[nh][j0 + 1], wd[nh][j0 + 3], false, false);
      union { unsigned u[4]; bf16x8 v; } pb;
      pb.u[0] = s1[0]; pb.u[1] = s2[0]; pb.u[2] = s1[1]; pb.u[3] = s2[1];
      Pb[c] = pb.v;
    }

    // ---- O^T += V^T * Pb ; lsum += ones * Pb ----
    __builtin_amdgcn_s_setprio(1);
    #pragma unroll
    for (int c = 0; c < 4; ++c) {
      bf16x8 vf0 = *(const bf16x8*)&Vs[bi][(lq) * 64      + (((c * 2 + hi) ^ (lq & 7)) * 8)];
      bf16x8 vf1 = *(const bf16x8*)&Vs[bi][(32 + lq) * 64 + (((c * 2 + hi) ^ (lq & 7)) * 8)];
      acc_l   = __builtin_amdgcn_mfma_f32_32x32x16_bf16(onesv, Pb[c], acc_l, 0, 0, 0);
      acco[0] = __builtin_amdgcn_mfma_f32_32x32x16_bf16(vf0, Pb[c], acco[0], 0, 0, 0);
      acco[1] = __builtin_amdgcn_mfma_f32_32x32x16_bf16(vf1, Pb[c], acco[1], 0, 0, 0);
    }
    __builtin_amdgcn_s_setprio(0);
  }
#undef STAGE

  // ---- epilogue: acc_l[any reg] = full denominator for q = lq ----
  float inv = 1.0f / acc_l[0];
  int s = q0 + w * 32 + lq;
  size_t base = ((size_t)b * SS + s) * D_MODEL + h * DKD;
  #pragma unroll
  for (int dh = 0; dh < 2; ++dh)
    #pragma unroll
    for (int g = 0; g < 4; ++g) {
      ushort4 o;
      o.x = f2bf(acco[dh][4 * g + 0] * inv);
      o.y = f2bf(acco[dh][4 * g + 1] * inv);
      o.z = f2bf(acco[dh][4 * g + 2] * inv);
      o.w = f2bf(acco[dh][4 * g + 3] * inv);
      *(ushort4*)(AO + base + dh * 32 + 4 * hi + 8 * g) = o;
    }
}

extern "C" void kernel_launch(void* const* d_in, const int* in_sizes, int n_in,
                              void* d_out, int out_size, void* d_ws, size_t ws_size,
                              hipStream_t stream) {
  const float* query = (const float*)d_in[0];
  const float* key_  = (const float*)d_in[1];
  const float* value = (const float*)d_in[2];
  const float* wts   = (const float*)d_in[3];
  const float* wq = (const float*)d_in[4];
  const float* bq = (const float*)d_in[5];
  const float* wk = (const float*)d_in[6];
  const float* bk = (const float*)d_in[7];
  const float* wv = (const float*)d_in[8];
  const float* bv = (const float*)d_in[9];
  const float* wo = (const float*)d_in[10];
  const float* bo = (const float*)d_in[11];
  float* out = (float*)d_out;

  char* ws = (char*)d_ws;
  const size_t MB = 1024 * 1024;
  u16* Xq  = (u16*)(ws + 0 * MB);
  u16* Xk  = (u16*)(ws + 8 * MB);
  u16* Xv  = (u16*)(ws + 16 * MB);   // dead after kgemm_qkv; reused as VtT
  u16* WqT = (u16*)(ws + 24 * MB);
  u16* WkT = (u16*)(ws + 26 * MB);
  u16* WvT = (u16*)(ws + 28 * MB);
  u16* WoT = (u16*)(ws + 30 * MB);
  u16* Qb  = (u16*)(ws + 32 * MB);
  u16* Kb  = (u16*)(ws + 40 * MB);
  u16* Vb  = (u16*)(ws + 48 * MB);
  u16* AO  = (u16*)(ws + 56 * MB);
  float* lwbuf = (float*)(ws + 64 * MB);
  u16* VtT = (u16*)(ws + 16 * MB);   // V transposed (b,h,dk,s), overwrites Xv after use

  kprep_conv<<<dim3(4096, 3), 256, 0, stream>>>(query, key_, value, Xq, Xk, Xv);
  kprep_wt<<<dim3(32, 32, 4), 256, 0, stream>>>(wq, wk, wv, wo, WqT, WkT, WvT, WoT);
  klw<<<16, 256, 0, stream>>>(wts, lwbuf);
  kgemm_qkv<<<dim3(8, 32, 3), 256, 0, stream>>>(Xq, Xk, Xv, WqT, WkT, WvT, bq, bk, bv, Qb, Kb, Vb);
  ktrans_v<<<dim3(32, 32), 256, 0, stream>>>(Vb, VtT);
  kattn<<<512, 256, 0, stream>>>(Qb, Kb, VtT, lwbuf, AO);
  kgemm_o<<<dim3(8, 32), 256, 0, stream>>>(AO, WoT, bo, out);
}

// Round 9
// 139.913 us; speedup vs baseline: 1.1138x; 1.1138x over previous
//
#include <hip/hip_runtime.h>

typedef unsigned short u16;
typedef __bf16 bf16x8 __attribute__((ext_vector_type(8)));
typedef float f32x4 __attribute__((ext_vector_type(4)));
typedef float f32x16 __attribute__((ext_vector_type(16)));

#define D_MODEL 1024
#define NH 16
#define DKD 64
#define BB 2
#define SS 2048
// log2(e)/8: folded into Q at projection time
#define QSCL 0.18033688011112042f

#if __has_builtin(__builtin_amdgcn_exp2f)
#define EXP2(x) __builtin_amdgcn_exp2f(x)
#else
#define EXP2(x) exp2f(x)
#endif

__device__ __forceinline__ u16 f2bf(float f) {
  union { float f; unsigned u; } x; x.f = f;
  unsigned r = x.u + 0x7fffu + ((x.u >> 16) & 1u);
  return (u16)(r >> 16);
}

__device__ __forceinline__ void gld16(const u16* g, u16* l) {
  __builtin_amdgcn_global_load_lds((__attribute__((address_space(1))) void*)(g),
                                   (__attribute__((address_space(3))) void*)(l),
                                   16, 0, 0);
}

// ---------------- prep: fp32 -> bf16 activation convert ----------------
extern "C" __global__ void __launch_bounds__(256) kprep_conv(
    const float* __restrict__ q, const float* __restrict__ k, const float* __restrict__ v,
    u16* __restrict__ xq, u16* __restrict__ xk, u16* __restrict__ xv)
{
  int z = blockIdx.y;
  const float* s = z == 0 ? q : (z == 1 ? k : v);
  u16* d = z == 0 ? xq : (z == 1 ? xk : xv);
  int i = (blockIdx.x * 256 + threadIdx.x) * 4;
  float4 val = *(const float4*)(s + i);
  ushort4 o;
  o.x = f2bf(val.x); o.y = f2bf(val.y); o.z = f2bf(val.z); o.w = f2bf(val.w);
  *(ushort4*)(d + i) = o;
}

// ---------------- prep: weight transpose + bf16 convert ----------------
extern "C" __global__ void __launch_bounds__(256) kprep_wt(
    const float* __restrict__ w0, const float* __restrict__ w1,
    const float* __restrict__ w2, const float* __restrict__ w3,
    u16* __restrict__ o0, u16* __restrict__ o1, u16* __restrict__ o2, u16* __restrict__ o3)
{
  const float* src; u16* dst;
  switch (blockIdx.z) {
    case 0: src = w0; dst = o0; break;
    case 1: src = w1; dst = o1; break;
    case 2: src = w2; dst = o2; break;
    default: src = w3; dst = o3; break;
  }
  __shared__ float t[32][33];
  int n0 = blockIdx.x * 32, k0 = blockIdx.y * 32;
  int tx = threadIdx.x & 31, ty = threadIdx.x >> 5;
  #pragma unroll
  for (int i = 0; i < 32; i += 8)
    t[ty + i][tx] = src[(k0 + ty + i) * D_MODEL + n0 + tx];
  __syncthreads();
  #pragma unroll
  for (int i = 0; i < 32; i += 8)
    dst[(size_t)(n0 + ty + i) * D_MODEL + k0 + tx] = f2bf(t[tx][ty + i]);
}

// ---------------- prep: log2(weights + 1e-20) - 16 (fixed-max softmax bias) ----------------
extern "C" __global__ void __launch_bounds__(256) klw(
    const float* __restrict__ w, float* __restrict__ lw)
{
  int i = blockIdx.x * 256 + threadIdx.x;
  if (i < BB * SS) lw[i] = log2f(w[i] + 1e-20f) - 16.0f;
}

// ---------------- V transpose: (b,h,s,dk) -> (b,h,dk,s) ----------------
extern "C" __global__ void __launch_bounds__(256) ktrans_v(
    const u16* __restrict__ src, u16* __restrict__ dst)
{
  __shared__ u16 T[64][72];
  int bh = blockIdx.y; int s0 = blockIdx.x * 64;
  int tid = threadIdx.x;
  int r = tid >> 3, c = (tid & 7) * 8;
  #pragma unroll
  for (int i = 0; i < 2; ++i)
    *(bf16x8*)&T[r + i * 32][c] = *(const bf16x8*)&src[((size_t)bh * SS + s0 + r + i * 32) * DKD + c];
  __syncthreads();
  #pragma unroll
  for (int i = 0; i < 2; ++i) {
    int dk = r + i * 32;
    ushort4 o0, o1;
    o0.x = T[c + 0][dk]; o0.y = T[c + 1][dk]; o0.z = T[c + 2][dk]; o0.w = T[c + 3][dk];
    o1.x = T[c + 4][dk]; o1.y = T[c + 5][dk]; o1.z = T[c + 6][dk]; o1.w = T[c + 7][dk];
    *(ushort4*)&dst[((size_t)bh * DKD + dk) * SS + s0 + c] = o0;
    *(ushort4*)&dst[((size_t)bh * DKD + dk) * SS + s0 + c + 4] = o1;
  }
}

// ---------------- shared GEMM core: C(128x128) = A(128xK) * Bt(128xK)^T ----------------
__device__ __forceinline__ void gemm_tile(const u16* __restrict__ Ag, const u16* __restrict__ Bg,
                                          u16* As, u16* Bs, f32x4 acc[4][4], int tid)
{
  int lane = tid & 63;
  int lr = lane & 15, lg = lane >> 4;
  int w = tid >> 6, wr = w >> 1, wc = w & 1;
  for (int k0 = 0; k0 < D_MODEL; k0 += 32) {
    #pragma unroll
    for (int c = 0; c < 2; ++c) {
      int idx = tid + c * 256;
      int row = idx >> 2, col = (idx & 3) * 8;
      gld16(Ag + row * D_MODEL + k0 + col, As + idx * 8);
      gld16(Bg + row * D_MODEL + k0 + col, Bs + idx * 8);
    }
    __syncthreads();
    bf16x8 af[4], bfr[4];
    #pragma unroll
    for (int mi = 0; mi < 4; ++mi)
      af[mi] = *(const bf16x8*)(As + (wr * 64 + mi * 16 + lr) * 32 + lg * 8);
    #pragma unroll
    for (int nj = 0; nj < 4; ++nj)
      bfr[nj] = *(const bf16x8*)(Bs + (wc * 64 + nj * 16 + lr) * 32 + lg * 8);
    #pragma unroll
    for (int mi = 0; mi < 4; ++mi)
      #pragma unroll
      for (int nj = 0; nj < 4; ++nj)
        acc[mi][nj] = __builtin_amdgcn_mfma_f32_16x16x32_bf16(af[mi], bfr[nj], acc[mi][nj], 0, 0, 0);
    __syncthreads();
  }
}

// ---------------- fused QKV projection ----------------
// z==0: Q scaled by QSCL. All outputs layout (b,h,s,dk).
extern "C" __global__ void __launch_bounds__(256) kgemm_qkv(
    const u16* __restrict__ xq, const u16* __restrict__ xk, const u16* __restrict__ xv,
    const u16* __restrict__ wqt, const u16* __restrict__ wkt, const u16* __restrict__ wvt,
    const float* __restrict__ bq, const float* __restrict__ bk, const float* __restrict__ bv,
    u16* __restrict__ Qb, u16* __restrict__ Kb, u16* __restrict__ Vb)
{
  __shared__ u16 As[128 * 32], Bs[128 * 32];
  int z = blockIdx.z;
  const u16* X  = z == 0 ? xq : (z == 1 ? xk : xv);
  const u16* Wt = z == 0 ? wqt : (z == 1 ? wkt : wvt);
  const float* bias = z == 0 ? bq : (z == 1 ? bk : bv);
  u16* dst = z == 0 ? Qb : (z == 1 ? Kb : Vb);
  int tid = threadIdx.x;
  f32x4 zero = {0.f, 0.f, 0.f, 0.f};
  f32x4 acc[4][4];
  #pragma unroll
  for (int i = 0; i < 4; ++i)
    #pragma unroll
    for (int j = 0; j < 4; ++j) acc[i][j] = zero;
  int m0 = blockIdx.y * 128, n0 = blockIdx.x * 128;
  gemm_tile(X + (size_t)m0 * D_MODEL, Wt + (size_t)n0 * D_MODEL, As, Bs, acc, tid);
  int lane = tid & 63, lr = lane & 15, lg = lane >> 4;
  int w = tid >> 6, wr = w >> 1, wc = w & 1;
  float scl = (z == 0) ? QSCL : 1.0f;
  #pragma unroll
  for (int mi = 0; mi < 4; ++mi)
    #pragma unroll
    for (int nj = 0; nj < 4; ++nj) {
      int n = n0 + wc * 64 + nj * 16 + lr;
      float bs = bias[n];
      int h = n >> 6, dk = n & 63;
      #pragma unroll
      for (int j = 0; j < 4; ++j) {
        int m = m0 + wr * 64 + mi * 16 + lg * 4 + j;
        int b = m >> 11, s = m & 2047;
        dst[(((size_t)(b * NH + h)) * SS + s) * DKD + dk] = f2bf((acc[mi][nj][j] + bs) * scl);
      }
    }
}

// ---------------- output projection ----------------
extern "C" __global__ void __launch_bounds__(256) kgemm_o(
    const u16* __restrict__ AO, const u16* __restrict__ wot,
    const float* __restrict__ bo, float* __restrict__ out)
{
  __shared__ u16 As[128 * 32], Bs[128 * 32];
  int tid = threadIdx.x;
  f32x4 zero = {0.f, 0.f, 0.f, 0.f};
  f32x4 acc[4][4];
  #pragma unroll
  for (int i = 0; i < 4; ++i)
    #pragma unroll
    for (int j = 0; j < 4; ++j) acc[i][j] = zero;
  int m0 = blockIdx.y * 128, n0 = blockIdx.x * 128;
  gemm_tile(AO + (size_t)m0 * D_MODEL, wot + (size_t)n0 * D_MODEL, As, Bs, acc, tid);
  int lane = tid & 63, lr = lane & 15, lg = lane >> 4;
  int w = tid >> 6, wr = w >> 1, wc = w & 1;
  #pragma unroll
  for (int mi = 0; mi < 4; ++mi)
    #pragma unroll
    for (int nj = 0; nj < 4; ++nj) {
      int n = n0 + wc * 64 + nj * 16 + lr;
      float bs = bo[n];
      #pragma unroll
      for (int j = 0; j < 4; ++j) {
        int m = m0 + wr * 64 + mi * 16 + lg * 4 + j;
        out[(size_t)m * D_MODEL + n] = acc[mi][nj][j] + bs;
      }
    }
}

// ---------------- flash attention: 32x32 MFMA, in-reg P, dbuf, 4 blocks/CU ----------------
// Qb: (b,h,s,dk) bf16 PRE-SCALED by log2(e)/8. Kb: (b,h,s,dk). Vt: (b,h,dk,s).
// lw2: (b,s) f32 = log2(w+1e-20)-16 (staged to LDS). AO: (b,s,1024) bf16.
// Per block: 128 q rows, 4 waves x 32q. Per 64-kv tile:
//   St[nh] = lw + K*Q^T  (2 x mfma32x32x16; C: col=q=lane&31, row=(r&3)+8(r>>2)+4hi)
//   p = v_exp_f32(St); per-lane f32 lsum partials; pack pairs -> Pb via permlane32_swap
//   O^T += V^T * Pb.  Epilogue: lsum across hi-halves via one shfl_xor(32).
// Pipeline: double-buffered K/V (L2-resident; depth-1 suffices), vmcnt(0)+barrier
// then STAGE(t+1) (R4-proven overwrite-safe ordering). LDS = 40960 B -> 4 blocks/CU.
extern "C" __global__ void __launch_bounds__(256, 4) kattn(
    const u16* __restrict__ Qb, const u16* __restrict__ Kb, const u16* __restrict__ Vt,
    const float* __restrict__ lw2, u16* __restrict__ AO)
{
  __shared__ __align__(16) u16 Ks[2][64 * 64];
  __shared__ __align__(16) u16 Vs[2][64 * 64];
  __shared__ __align__(16) float lwf[SS];

  int tid = threadIdx.x, lane = tid & 63, w = tid >> 6;  // w 0..3
  int lq = lane & 31, hi = lane >> 5;

  // XCD-clustered decode: each XCD owns 4 heads x all 16 q-tiles (K/V L2-resident)
  int n = blockIdx.x;                  // 0..511
  int xcd = n & 7, slot = n >> 3;
  int bh = xcd + 8 * (slot >> 4);
  int q0 = (slot & 15) * 128;
  int b = bh >> 4, h = bh & 15;

  const u16* Qg = Qb + ((size_t)bh * SS + q0 + w * 32) * DKD;
  const u16* Kg = Kb + (size_t)bh * SS * DKD;
  const u16* Vg = Vt + (size_t)bh * DKD * SS;   // rows = dk, cols = s
  const float* lwb = lw2 + b * SS;

  // stage lw row into LDS
  #pragma unroll
  for (int i = 0; i < 2; ++i) {
    int idx = tid + i * 256;
    *(float4*)&lwf[idx * 4] = *(const float4*)(lwb + idx * 4);
  }

  // Q B-frags: B[k = kc*16 + hi*8 + i][q = lq]
  bf16x8 qf[4];
  #pragma unroll
  for (int kc = 0; kc < 4; ++kc)
    qf[kc] = *(const bf16x8*)(Qg + lq * DKD + kc * 16 + hi * 8);

  f32x16 acco[2] = {};
  float lsp[4] = {0.f, 0.f, 0.f, 0.f};

  // staging: LDS[row][c3] = Global[row][c3 ^ (row&7)] (linear dest for gld16)
  int srow0 = tid >> 3, sc0 = ((tid & 7) ^ (srow0 & 7)) * 8;
  int srow1 = srow0 + 32, sc1 = ((tid & 7) ^ (srow1 & 7)) * 8;

#define STAGE(t, bi) do { \
    gld16(Kg + (size_t)((t) * 64 + srow0) * DKD + sc0, &Ks[bi][tid * 8]); \
    gld16(Kg + (size_t)((t) * 64 + srow1) * DKD + sc1, &Ks[bi][(tid + 256) * 8]); \
    gld16(Vg + (size_t)srow0 * SS + (t) * 64 + sc0, &Vs[bi][tid * 8]); \
    gld16(Vg + (size_t)srow1 * SS + (t) * 64 + sc1, &Vs[bi][(tid + 256) * 8]); \
  } while (0)

  const int NT = SS / 64;
  STAGE(0, 0);
  for (int t = 0; t < NT; ++t) {
    // current tile's loads done (they had a full compute phase; L2-resident)
    asm volatile("s_waitcnt vmcnt(0) lgkmcnt(0)" ::: "memory");
    __builtin_amdgcn_s_barrier();     // also: everyone done reading buf (t-1)&1
    __builtin_amdgcn_sched_barrier(0);
    if (t + 1 < NT) STAGE(t + 1, (t + 1) & 1);   // writes buf != current
    int bi = t & 1;
    int kv0 = t * 64;

    // ---- St[nh] init from lw: row(reg r) = (r&3) + 8*(r>>2) + 4*hi ----
    f32x16 st[2];
    #pragma unroll
    for (int nh = 0; nh < 2; ++nh)
      #pragma unroll
      for (int g = 0; g < 4; ++g) {
        f32x4 lv = *(const f32x4*)&lwf[kv0 + nh * 32 + 4 * hi + 8 * g];
        st[nh][4 * g + 0] = lv[0]; st[nh][4 * g + 1] = lv[1];
        st[nh][4 * g + 2] = lv[2]; st[nh][4 * g + 3] = lv[3];
      }

    // ---- St += K * Q^T ----
    __builtin_amdgcn_s_setprio(1);
    #pragma unroll
    for (int kc = 0; kc < 4; ++kc) {
      bf16x8 kf0 = *(const bf16x8*)&Ks[bi][(lq) * 64      + (((kc * 2 + hi) ^ (lq & 7)) * 8)];
      bf16x8 kf1 = *(const bf16x8*)&Ks[bi][(32 + lq) * 64 + (((kc * 2 + hi) ^ (lq & 7)) * 8)];
      st[0] = __builtin_amdgcn_mfma_f32_32x32x16_bf16(kf0, qf[kc], st[0], 0, 0, 0);
      st[1] = __builtin_amdgcn_mfma_f32_32x32x16_bf16(kf1, qf[kc], st[1], 0, 0, 0);
    }
    __builtin_amdgcn_s_setprio(0);

    // ---- p = exp2(st) (single v_exp_f32); per-lane lsum partials; pack pairs ----
    unsigned wd[2][8];
    #pragma unroll
    for (int nh = 0; nh < 2; ++nh)
      #pragma unroll
      for (int r2 = 0; r2 < 8; ++r2) {
        float plo = EXP2(st[nh][2 * r2]);
        float phi = EXP2(st[nh][2 * r2 + 1]);
        lsp[r2 & 3] += plo + phi;
        union { unsigned u; __bf16 b2[2]; } cv;
        cv.b2[0] = (__bf16)plo; cv.b2[1] = (__bf16)phi;
        wd[nh][r2] = cv.u;
      }

    // ---- Pb[c] B-frags via permlane32_swap ----
    // chunk c: kv = c*16 + hi*8 + i; nh = c>>1, j0 = 4*(c&1)
    // s1 = swap(wd[j0], wd[j0+2]): s1[0]={a_lo,b_lo} -> slots 0,1 ; s1[1]={a_hi,b_hi} -> slots 4,5
    bf16x8 Pb[4];
    #pragma unroll
    for (int c = 0; c < 4; ++c) {
      int nh = c >> 1, j0 = 4 * (c & 1);
      auto s1 = __builtin_amdgcn_permlane32_swap(wd[nh][j0 + 0], wd[nh][j0 + 2], false, false);
      auto s2 = __builtin_amdgcn_permlane32_swap(wd[nh][j0 + 1], wd[nh][j0 + 3], false, false);
      union { unsigned u[4]; bf16x8 v; } pb;
      pb.u[0] = s1[0]; pb.u[1] = s2[0]; pb.u[2] = s1[1]; pb.u[3] = s2[1];
      Pb[c] = pb.v;
    }

    // ---- O^T += V^T * Pb ----
    __builtin_amdgcn_s_setprio(1);
    #pragma unroll
    for (int c = 0; c < 4; ++c) {
      bf16x8 vf0 = *(const bf16x8*)&Vs[bi][(lq) * 64      + (((c * 2 + hi) ^ (lq & 7)) * 8)];
      bf16x8 vf1 = *(const bf16x8*)&Vs[bi][(32 + lq) * 64 + (((c * 2 + hi) ^ (lq & 7)) * 8)];
      acco[0] = __builtin_amdgcn_mfma_f32_32x32x16_bf16(vf0, Pb[c], acco[0], 0, 0, 0);
      acco[1] = __builtin_amdgcn_mfma_f32_32x32x16_bf16(vf1, Pb[c], acco[1], 0, 0, 0);
    }
    __builtin_amdgcn_s_setprio(0);
  }
#undef STAGE

  // ---- epilogue: lsum(q=lq) = own-half partials + other-half via shfl_xor(32) ----
  float lsum = (lsp[0] + lsp[1]) + (lsp[2] + lsp[3]);
  lsum += __shfl_xor(lsum, 32);
  float inv = 1.0f / lsum;
  int s = q0 + w * 32 + lq;
  size_t base = ((size_t)b * SS + s) * D_MODEL + h * DKD;
  #pragma unroll
  for (int dh = 0; dh < 2; ++dh)
    #pragma unroll
    for (int g = 0; g < 4; ++g) {
      ushort4 o;
      o.x = f2bf(acco[dh][4 * g + 0] * inv);
      o.y = f2bf(acco[dh][4 * g + 1] * inv);
      o.z = f2bf(acco[dh][4 * g + 2] * inv);
      o.w = f2bf(acco[dh][4 * g + 3] * inv);
      *(ushort4*)(AO + base + dh * 32 + 4 * hi + 8 * g) = o;
    }
}

extern "C" void kernel_launch(void* const* d_in, const int* in_sizes, int n_in,
                              void* d_out, int out_size, void* d_ws, size_t ws_size,
                              hipStream_t stream) {
  const float* query = (const float*)d_in[0];
  const float* key_  = (const float*)d_in[1];
  const float* value = (const float*)d_in[2];
  const float* wts   = (const float*)d_in[3];
  const float* wq = (const float*)d_in[4];
  const float* bq = (const float*)d_in[5];
  const float* wk = (const float*)d_in[6];
  const float* bk = (const float*)d_in[7];
  const float* wv = (const float*)d_in[8];
  const float* bv = (const float*)d_in[9];
  const float* wo = (const float*)d_in[10];
  const float* bo = (const float*)d_in[11];
  float* out = (float*)d_out;

  char* ws = (char*)d_ws;
  const size_t MB = 1024 * 1024;
  u16* Xq  = (u16*)(ws + 0 * MB);
  u16* Xk  = (u16*)(ws + 8 * MB);
  u16* Xv  = (u16*)(ws + 16 * MB);   // dead after kgemm_qkv; reused as VtT
  u16* WqT = (u16*)(ws + 24 * MB);
  u16* WkT = (u16*)(ws + 26 * MB);
  u16* WvT = (u16*)(ws + 28 * MB);
  u16* WoT = (u16*)(ws + 30 * MB);
  u16* Qb  = (u16*)(ws + 32 * MB);
  u16* Kb  = (u16*)(ws + 40 * MB);
  u16* Vb  = (u16*)(ws + 48 * MB);
  u16* AO  = (u16*)(ws + 56 * MB);
  float* lwbuf = (float*)(ws + 64 * MB);
  u16* VtT = (u16*)(ws + 16 * MB);   // V transposed (b,h,dk,s), overwrites Xv after use

  kprep_conv<<<dim3(4096, 3), 256, 0, stream>>>(query, key_, value, Xq, Xk, Xv);
  kprep_wt<<<dim3(32, 32, 4), 256, 0, stream>>>(wq, wk, wv, wo, WqT, WkT, WvT, WoT);
  klw<<<16, 256, 0, stream>>>(wts, lwbuf);
  kgemm_qkv<<<dim3(8, 32, 3), 256, 0, stream>>>(Xq, Xk, Xv, WqT, WkT, WvT, bq, bk, bv, Qb, Kb, Vb);
  ktrans_v<<<dim3(32, 32), 256, 0, stream>>>(Vb, VtT);
  kattn<<<512, 256, 0, stream>>>(Qb, Kb, VtT, lwbuf, AO);
  kgemm_o<<<dim3(8, 32), 256, 0, stream>>>(AO, WoT, bo, out);
}

// Round 10
// 134.886 us; speedup vs baseline: 1.1553x; 1.0373x over previous
//
#include <hip/hip_runtime.h>

typedef unsigned short u16;
typedef __bf16 bf16x8 __attribute__((ext_vector_type(8)));
typedef float f32x4 __attribute__((ext_vector_type(4)));
typedef float f32x16 __attribute__((ext_vector_type(16)));

#define D_MODEL 1024
#define NH 16
#define DKD 64
#define BB 2
#define SS 2048
// log2(e)/8: folded into Q at projection time
#define QSCL 0.18033688011112042f

#if __has_builtin(__builtin_amdgcn_exp2f)
#define EXP2(x) __builtin_amdgcn_exp2f(x)
#else
#define EXP2(x) exp2f(x)
#endif

__device__ __forceinline__ u16 f2bf(float f) {
  union { float f; unsigned u; } x; x.f = f;
  unsigned r = x.u + 0x7fffu + ((x.u >> 16) & 1u);
  return (u16)(r >> 16);
}

__device__ __forceinline__ void gld16(const u16* g, u16* l) {
  __builtin_amdgcn_global_load_lds((__attribute__((address_space(1))) void*)(g),
                                   (__attribute__((address_space(3))) void*)(l),
                                   16, 0, 0);
}

// ---------------- prep: fp32 -> bf16 convert (+ folded lw compute in block 4096) ----------------
extern "C" __global__ void __launch_bounds__(256) kprep_conv(
    const float* __restrict__ q, const float* __restrict__ k, const float* __restrict__ v,
    const float* __restrict__ wts,
    u16* __restrict__ xq, u16* __restrict__ xk, u16* __restrict__ xv,
    float* __restrict__ lw)
{
  int z = blockIdx.y;
  if (blockIdx.x == 4096) {            // folded klw: 4096 elems, z==0 only
    if (z == 0) {
      int i = threadIdx.x * 16;
      #pragma unroll
      for (int j = 0; j < 16; j += 4) {
        float4 val = *(const float4*)(wts + i + j);
        lw[i + j + 0] = log2f(val.x + 1e-20f) - 16.0f;
        lw[i + j + 1] = log2f(val.y + 1e-20f) - 16.0f;
        lw[i + j + 2] = log2f(val.z + 1e-20f) - 16.0f;
        lw[i + j + 3] = log2f(val.w + 1e-20f) - 16.0f;
      }
    }
    return;
  }
  const float* s = z == 0 ? q : (z == 1 ? k : v);
  u16* d = z == 0 ? xq : (z == 1 ? xk : xv);
  int i = (blockIdx.x * 256 + threadIdx.x) * 4;
  float4 val = *(const float4*)(s + i);
  ushort4 o;
  o.x = f2bf(val.x); o.y = f2bf(val.y); o.z = f2bf(val.z); o.w = f2bf(val.w);
  *(ushort4*)(d + i) = o;
}

// ---------------- prep: weight transpose + bf16 convert ----------------
extern "C" __global__ void __launch_bounds__(256) kprep_wt(
    const float* __restrict__ w0, const float* __restrict__ w1,
    const float* __restrict__ w2, const float* __restrict__ w3,
    u16* __restrict__ o0, u16* __restrict__ o1, u16* __restrict__ o2, u16* __restrict__ o3)
{
  const float* src; u16* dst;
  switch (blockIdx.z) {
    case 0: src = w0; dst = o0; break;
    case 1: src = w1; dst = o1; break;
    case 2: src = w2; dst = o2; break;
    default: src = w3; dst = o3; break;
  }
  __shared__ float t[32][33];
  int n0 = blockIdx.x * 32, k0 = blockIdx.y * 32;
  int tx = threadIdx.x & 31, ty = threadIdx.x >> 5;
  #pragma unroll
  for (int i = 0; i < 32; i += 8)
    t[ty + i][tx] = src[(k0 + ty + i) * D_MODEL + n0 + tx];
  __syncthreads();
  #pragma unroll
  for (int i = 0; i < 32; i += 8)
    dst[(size_t)(n0 + ty + i) * D_MODEL + k0 + tx] = f2bf(t[tx][ty + i]);
}

// ---------------- V transpose: (b,h,s,dk) -> (b,h,dk,s) ----------------
extern "C" __global__ void __launch_bounds__(256) ktrans_v(
    const u16* __restrict__ src, u16* __restrict__ dst)
{
  __shared__ u16 T[64][72];
  int bh = blockIdx.y; int s0 = blockIdx.x * 64;
  int tid = threadIdx.x;
  int r = tid >> 3, c = (tid & 7) * 8;
  #pragma unroll
  for (int i = 0; i < 2; ++i)
    *(bf16x8*)&T[r + i * 32][c] = *(const bf16x8*)&src[((size_t)bh * SS + s0 + r + i * 32) * DKD + c];
  __syncthreads();
  #pragma unroll
  for (int i = 0; i < 2; ++i) {
    int dk = r + i * 32;
    ushort4 o0, o1;
    o0.x = T[c + 0][dk]; o0.y = T[c + 1][dk]; o0.z = T[c + 2][dk]; o0.w = T[c + 3][dk];
    o1.x = T[c + 4][dk]; o1.y = T[c + 5][dk]; o1.z = T[c + 6][dk]; o1.w = T[c + 7][dk];
    *(ushort4*)&dst[((size_t)bh * DKD + dk) * SS + s0 + c] = o0;
    *(ushort4*)&dst[((size_t)bh * DKD + dk) * SS + s0 + c + 4] = o1;
  }
}

// ---------------- shared GEMM core: C(128x128) = A(128xK) * Bt(128xK)^T ----------------
__device__ __forceinline__ void gemm_tile(const u16* __restrict__ Ag, const u16* __restrict__ Bg,
                                          u16* As, u16* Bs, f32x4 acc[4][4], int tid)
{
  int lane = tid & 63;
  int lr = lane & 15, lg = lane >> 4;
  int w = tid >> 6, wr = w >> 1, wc = w & 1;
  for (int k0 = 0; k0 < D_MODEL; k0 += 32) {
    #pragma unroll
    for (int c = 0; c < 2; ++c) {
      int idx = tid + c * 256;
      int row = idx >> 2, col = (idx & 3) * 8;
      gld16(Ag + row * D_MODEL + k0 + col, As + idx * 8);
      gld16(Bg + row * D_MODEL + k0 + col, Bs + idx * 8);
    }
    __syncthreads();
    bf16x8 af[4], bfr[4];
    #pragma unroll
    for (int mi = 0; mi < 4; ++mi)
      af[mi] = *(const bf16x8*)(As + (wr * 64 + mi * 16 + lr) * 32 + lg * 8);
    #pragma unroll
    for (int nj = 0; nj < 4; ++nj)
      bfr[nj] = *(const bf16x8*)(Bs + (wc * 64 + nj * 16 + lr) * 32 + lg * 8);
    #pragma unroll
    for (int mi = 0; mi < 4; ++mi)
      #pragma unroll
      for (int nj = 0; nj < 4; ++nj)
        acc[mi][nj] = __builtin_amdgcn_mfma_f32_16x16x32_bf16(af[mi], bfr[nj], acc[mi][nj], 0, 0, 0);
    __syncthreads();
  }
}

// ---------------- fused QKV projection ----------------
// z==0: Q scaled by QSCL. All outputs layout (b,h,s,dk).
extern "C" __global__ void __launch_bounds__(256) kgemm_qkv(
    const u16* __restrict__ xq, const u16* __restrict__ xk, const u16* __restrict__ xv,
    const u16* __restrict__ wqt, const u16* __restrict__ wkt, const u16* __restrict__ wvt,
    const float* __restrict__ bq, const float* __restrict__ bk, const float* __restrict__ bv,
    u16* __restrict__ Qb, u16* __restrict__ Kb, u16* __restrict__ Vb)
{
  __shared__ u16 As[128 * 32], Bs[128 * 32];
  int z = blockIdx.z;
  const u16* X  = z == 0 ? xq : (z == 1 ? xk : xv);
  const u16* Wt = z == 0 ? wqt : (z == 1 ? wkt : wvt);
  const float* bias = z == 0 ? bq : (z == 1 ? bk : bv);
  u16* dst = z == 0 ? Qb : (z == 1 ? Kb : Vb);
  int tid = threadIdx.x;
  f32x4 zero = {0.f, 0.f, 0.f, 0.f};
  f32x4 acc[4][4];
  #pragma unroll
  for (int i = 0; i < 4; ++i)
    #pragma unroll
    for (int j = 0; j < 4; ++j) acc[i][j] = zero;
  int m0 = blockIdx.y * 128, n0 = blockIdx.x * 128;
  gemm_tile(X + (size_t)m0 * D_MODEL, Wt + (size_t)n0 * D_MODEL, As, Bs, acc, tid);
  int lane = tid & 63, lr = lane & 15, lg = lane >> 4;
  int w = tid >> 6, wr = w >> 1, wc = w & 1;
  float scl = (z == 0) ? QSCL : 1.0f;
  #pragma unroll
  for (int mi = 0; mi < 4; ++mi)
    #pragma unroll
    for (int nj = 0; nj < 4; ++nj) {
      int n = n0 + wc * 64 + nj * 16 + lr;
      float bs = bias[n];
      int h = n >> 6, dk = n & 63;
      #pragma unroll
      for (int j = 0; j < 4; ++j) {
        int m = m0 + wr * 64 + mi * 16 + lg * 4 + j;
        int b = m >> 11, s = m & 2047;
        dst[(((size_t)(b * NH + h)) * SS + s) * DKD + dk] = f2bf((acc[mi][nj][j] + bs) * scl);
      }
    }
}

// ---------------- output projection ----------------
extern "C" __global__ void __launch_bounds__(256) kgemm_o(
    const u16* __restrict__ AO, const u16* __restrict__ wot,
    const float* __restrict__ bo, float* __restrict__ out)
{
  __shared__ u16 As[128 * 32], Bs[128 * 32];
  int tid = threadIdx.x;
  f32x4 zero = {0.f, 0.f, 0.f, 0.f};
  f32x4 acc[4][4];
  #pragma unroll
  for (int i = 0; i < 4; ++i)
    #pragma unroll
    for (int j = 0; j < 4; ++j) acc[i][j] = zero;
  int m0 = blockIdx.y * 128, n0 = blockIdx.x * 128;
  gemm_tile(AO + (size_t)m0 * D_MODEL, wot + (size_t)n0 * D_MODEL, As, Bs, acc, tid);
  int lane = tid & 63, lr = lane & 15, lg = lane >> 4;
  int w = tid >> 6, wr = w >> 1, wc = w & 1;
  #pragma unroll
  for (int mi = 0; mi < 4; ++mi)
    #pragma unroll
    for (int nj = 0; nj < 4; ++nj) {
      int n = n0 + wc * 64 + nj * 16 + lr;
      float bs = bo[n];
      #pragma unroll
      for (int j = 0; j < 4; ++j) {
        int m = m0 + wr * 64 + mi * 16 + lg * 4 + j;
        out[(size_t)m * D_MODEL + n] = acc[mi][nj][j] + bs;
      }
    }
}

// ---------------- flash attention: 8 waves, kv-parity split, 4-slot ring, 16 waves/CU ----------------
// Qb: (b,h,s,dk) bf16 PRE-SCALED by log2(e)/8. Kb: (b,h,s,dk). Vt: (b,h,dk,s).
// lw2: (b,s) f32 = log2(w+1e-20)-16 (staged to LDS). AO: (b,s,1024) bf16.
// Block: 512 thr, 8 waves. qw = w&3 (q col group of 32), par = w>>2 (kv tile parity).
// Waves par=0 compute even kv tiles, par=1 odd tiles -- two tiles in flight per block.
// Per tile per wave (identical math to R9): St = lw + K*Q^T (2x mfma32x32x16),
// p = v_exp_f32, per-lane lsum partials, Pb via permlane32_swap, O^T += V^T*Pb.
// Ring: 4 slots; super-iter i: [vmcnt(4); barrier; compute 2i+par; barrier; STAGE 2i+4,2i+5].
// Epilogue: parity partners combine acco+lsum via LDS (stride 34), par=0 stores.
extern "C" __global__ void __launch_bounds__(512, 4) kattn(
    const u16* __restrict__ Qb, const u16* __restrict__ Kb, const u16* __restrict__ Vt,
    const float* __restrict__ lw2, u16* __restrict__ AO)
{
  __shared__ __align__(16) char smem[4 * 16384 + 8192];  // 4 K/V slots (16KB each) + lwf
  float* lwf = (float*)(smem + 65536);

  int tid = threadIdx.x, lane = tid & 63, w = tid >> 6;  // w 0..7
  int lq = lane & 31, hi = lane >> 5;
  int qw = w & 3, par = w >> 2;

  // XCD-clustered decode: each XCD owns 4 heads x all 16 q-tiles (K/V L2-resident)
  int n = blockIdx.x;                  // 0..511
  int xcd = n & 7, slot = n >> 3;
  int bh = xcd + 8 * (slot >> 4);
  int q0 = (slot & 15) * 128;
  int b = bh >> 4, h = bh & 15;

  const u16* Qg = Qb + ((size_t)bh * SS + q0 + qw * 32) * DKD;
  const u16* Kg = Kb + (size_t)bh * SS * DKD;
  const u16* Vg = Vt + (size_t)bh * DKD * SS;   // rows = dk, cols = s
  const float* lwb = lw2 + b * SS;

  // stage lw row into LDS (512 threads x 1 float4)
  *(float4*)&lwf[tid * 4] = *(const float4*)(lwb + tid * 4);

  // Q B-frags: B[k = kc*16 + hi*8 + i][q = lq]
  bf16x8 qf[4];
  #pragma unroll
  for (int kc = 0; kc < 4; ++kc)
    qf[kc] = *(const bf16x8*)(Qg + lq * DKD + kc * 16 + hi * 8);

  f32x16 acco[2] = {};
  float lsp[4] = {0.f, 0.f, 0.f, 0.f};

  // staging: 512 threads x (1 K chunk + 1 V chunk) per tile
  // LDS[row][c3] = Global[row][c3 ^ (row&7)] (linear dest for gld16; swizzle on src+read)
  int srow = tid >> 3, sc = ((tid & 7) ^ (srow & 7)) * 8;

#define KSLOT(sl) ((u16*)(smem + (sl) * 16384))
#define VSLOT(sl) ((u16*)(smem + (sl) * 16384 + 8192))
#define STAGE(t, sl) do { \
    gld16(Kg + (size_t)((t) * 64 + srow) * DKD + sc, KSLOT(sl) + tid * 8); \
    gld16(Vg + (size_t)srow * SS + (t) * 64 + sc, VSLOT(sl) + tid * 8); \
  } while (0)

  STAGE(0, 0); STAGE(1, 1); STAGE(2, 2); STAGE(3, 3);
  for (int i = 0; i < 16; ++i) {
    // need tiles 2i,2i+1 done; <=4 newer loads (tiles 2i+2,2i+3) may stay in flight
    if (i < 15) asm volatile("s_waitcnt vmcnt(4) lgkmcnt(0)" ::: "memory");
    else        asm volatile("s_waitcnt vmcnt(0) lgkmcnt(0)" ::: "memory");
    __builtin_amdgcn_s_barrier();
    __builtin_amdgcn_sched_barrier(0);

    int t = 2 * i + par;
    int bi = t & 3;
    int kv0 = t * 64;
    const u16* Kp = KSLOT(bi);
    const u16* Vp = VSLOT(bi);

    // ---- St init from lw: row(reg r) = (r&3) + 8*(r>>2) + 4*hi ----
    f32x16 st[2];
    #pragma unroll
    for (int nh = 0; nh < 2; ++nh)
      #pragma unroll
      for (int g = 0; g < 4; ++g) {
        f32x4 lv = *(const f32x4*)&lwf[kv0 + nh * 32 + 4 * hi + 8 * g];
        st[nh][4 * g + 0] = lv[0]; st[nh][4 * g + 1] = lv[1];
        st[nh][4 * g + 2] = lv[2]; st[nh][4 * g + 3] = lv[3];
      }

    // ---- St += K * Q^T ----
    __builtin_amdgcn_s_setprio(1);
    #pragma unroll
    for (int kc = 0; kc < 4; ++kc) {
      bf16x8 kf0 = *(const bf16x8*)&Kp[(lq) * 64      + (((kc * 2 + hi) ^ (lq & 7)) * 8)];
      bf16x8 kf1 = *(const bf16x8*)&Kp[(32 + lq) * 64 + (((kc * 2 + hi) ^ (lq & 7)) * 8)];
      st[0] = __builtin_amdgcn_mfma_f32_32x32x16_bf16(kf0, qf[kc], st[0], 0, 0, 0);
      st[1] = __builtin_amdgcn_mfma_f32_32x32x16_bf16(kf1, qf[kc], st[1], 0, 0, 0);
    }
    __builtin_amdgcn_s_setprio(0);

    // ---- p = exp2(st) (single v_exp_f32); per-lane lsum partials; pack pairs ----
    unsigned wd[2][8];
    #pragma unroll
    for (int nh = 0; nh < 2; ++nh)
      #pragma unroll
      for (int r2 = 0; r2 < 8; ++r2) {
        float plo = EXP2(st[nh][2 * r2]);
        float phi = EXP2(st[nh][2 * r2 + 1]);
        lsp[r2 & 3] += plo + phi;
        union { unsigned u; __bf16 b2[2]; } cv;
        cv.b2[0] = (__bf16)plo; cv.b2[1] = (__bf16)phi;
        wd[nh][r2] = cv.u;
      }

    // ---- Pb[c] B-frags via permlane32_swap ----
    bf16x8 Pb[4];
    #pragma unroll
    for (int c = 0; c < 4; ++c) {
      int nh = c >> 1, j0 = 4 * (c & 1);
      auto s1 = __builtin_amdgcn_permlane32_swap(wd[nh][j0 + 0], wd[nh][j0 + 2], false, false);
      auto s2 = __builtin_amdgcn_permlane32_swap(wd[nh][j0 + 1], wd[nh][j0 + 3], false, false);
      union { unsigned u[4]; bf16x8 v; } pb;
      pb.u[0] = s1[0]; pb.u[1] = s2[0]; pb.u[2] = s1[1]; pb.u[3] = s2[1];
      Pb[c] = pb.v;
    }

    // ---- O^T += V^T * Pb ----
    __builtin_amdgcn_s_setprio(1);
    #pragma unroll
    for (int c = 0; c < 4; ++c) {
      bf16x8 vf0 = *(const bf16x8*)&Vp[(lq) * 64      + (((c * 2 + hi) ^ (lq & 7)) * 8)];
      bf16x8 vf1 = *(const bf16x8*)&Vp[(32 + lq) * 64 + (((c * 2 + hi) ^ (lq & 7)) * 8)];
      acco[0] = __builtin_amdgcn_mfma_f32_32x32x16_bf16(vf0, Pb[c], acco[0], 0, 0, 0);
      acco[1] = __builtin_amdgcn_mfma_f32_32x32x16_bf16(vf1, Pb[c], acco[1], 0, 0, 0);
    }
    __builtin_amdgcn_s_setprio(0);

    // all waves done reading slots (2i)&3,(2i+1)&3 before tail restages them
    __builtin_amdgcn_sched_barrier(0);
    __builtin_amdgcn_s_barrier();
    int tn = 2 * i + 4;
    if (tn < 32) { STAGE(tn, tn & 3); STAGE(tn + 1, (tn + 1) & 3); }
  }
#undef STAGE

  // ---- epilogue: combine parity partners via LDS (stride 34 f32), par=0 stores ----
  float lsum_part = (lsp[0] + lsp[1]) + (lsp[2] + lsp[3]);
  float* comb = (float*)smem;          // slots dead; 4*64*34*4 = 34.8KB < 64KB
  int coff = (qw * 64 + lane) * 34;
  if (par == 1) {
    #pragma unroll
    for (int d = 0; d < 2; ++d)
      #pragma unroll
      for (int g = 0; g < 8; ++g)
        *(float2*)&comb[coff + (d * 8 + g) * 2] = make_float2(acco[d][2 * g], acco[d][2 * g + 1]);
    comb[coff + 32] = lsum_part;
  }
  __syncthreads();
  if (par == 0) {
    #pragma unroll
    for (int d = 0; d < 2; ++d)
      #pragma unroll
      for (int g = 0; g < 8; ++g) {
        float2 v = *(const float2*)&comb[coff + (d * 8 + g) * 2];
        acco[d][2 * g] += v.x; acco[d][2 * g + 1] += v.y;
      }
    lsum_part += comb[coff + 32];
    float lsum = lsum_part + __shfl_xor(lsum_part, 32);
    float inv = 1.0f / lsum;
    int s = q0 + qw * 32 + lq;
    size_t base = ((size_t)b * SS + s) * D_MODEL + h * DKD;
    #pragma unroll
    for (int dh = 0; dh < 2; ++dh)
      #pragma unroll
      for (int g = 0; g < 4; ++g) {
        ushort4 o;
        o.x = f2bf(acco[dh][4 * g + 0] * inv);
        o.y = f2bf(acco[dh][4 * g + 1] * inv);
        o.z = f2bf(acco[dh][4 * g + 2] * inv);
        o.w = f2bf(acco[dh][4 * g + 3] * inv);
        *(ushort4*)(AO + base + dh * 32 + 4 * hi + 8 * g) = o;
      }
  }
#undef KSLOT
#undef VSLOT
}

extern "C" void kernel_launch(void* const* d_in, const int* in_sizes, int n_in,
                              void* d_out, int out_size, void* d_ws, size_t ws_size,
                              hipStream_t stream) {
  const float* query = (const float*)d_in[0];
  const float* key_  = (const float*)d_in[1];
  const float* value = (const float*)d_in[2];
  const float* wts   = (const float*)d_in[3];
  const float* wq = (const float*)d_in[4];
  const float* bq = (const float*)d_in[5];
  const float* wk = (const float*)d_in[6];
  const float* bk = (const float*)d_in[7];
  const float* wv = (const float*)d_in[8];
  const float* bv = (const float*)d_in[9];
  const float* wo = (const float*)d_in[10];
  const float* bo = (const float*)d_in[11];
  float* out = (float*)d_out;

  char* ws = (char*)d_ws;
  const size_t MB = 1024 * 1024;
  u16* Xq  = (u16*)(ws + 0 * MB);
  u16* Xk  = (u16*)(ws + 8 * MB);
  u16* Xv  = (u16*)(ws + 16 * MB);   // dead after kgemm_qkv; reused as VtT
  u16* WqT = (u16*)(ws + 24 * MB);
  u16* WkT = (u16*)(ws + 26 * MB);
  u16* WvT = (u16*)(ws + 28 * MB);
  u16* WoT = (u16*)(ws + 30 * MB);
  u16* Qb  = (u16*)(ws + 32 * MB);
  u16* Kb  = (u16*)(ws + 40 * MB);
  u16* Vb  = (u16*)(ws + 48 * MB);
  u16* AO  = (u16*)(ws + 56 * MB);
  float* lwbuf = (float*)(ws + 64 * MB);
  u16* VtT = (u16*)(ws + 16 * MB);   // V transposed (b,h,dk,s), overwrites Xv after use

  kprep_conv<<<dim3(4097, 3), 256, 0, stream>>>(query, key_, value, wts, Xq, Xk, Xv, lwbuf);
  kprep_wt<<<dim3(32, 32, 4), 256, 0, stream>>>(wq, wk, wv, wo, WqT, WkT, WvT, WoT);
  kgemm_qkv<<<dim3(8, 32, 3), 256, 0, stream>>>(Xq, Xk, Xv, WqT, WkT, WvT, bq, bk, bv, Qb, Kb, Vb);
  ktrans_v<<<dim3(32, 32), 256, 0, stream>>>(Vb, VtT);
  kattn<<<512, 512, 0, stream>>>(Qb, Kb, VtT, lwbuf, AO);
  kgemm_o<<<dim3(8, 32), 256, 0, stream>>>(AO, WoT, bo, out);
}